// Round 3
// baseline (1214.609 us; speedup 1.0000x reference)
//
#include <hip/hip_runtime.h>
#include <hip/hip_bf16.h>

// LSTM: B=256, T=512, I=256, H=128 (4H=512 gates), then MLP 128->64->32->4.
// ROUND 11:
//   * LSTM role: 2-group software pipeline. The block's 4 batch rows split
//     into groups {0,1},{2,3}. Phase p: MFMA(group cg) + gate-math(group
//     1-cg) using the PREVIOUS phase's MFMA results -> every latency
//     (ds_read h, 4-deep MFMA chain, exp/tanh) has a full phase of slack.
//     129 half-phases, issue-bound (~450cy) instead of 64 latency-bound
//     steps (~2170cy). Mod-2 B-col replication: lane u owns unit
//     (j=16w+(u>>2), b=2g+(u&1)); lanes u,u+2 duplicate (writes predicated).
//     gx: one dwordx2 @ shortoff 4*jl covers all 4 batches (both groups).
//   * Prologue: convert blocks INTERLEAVED with GEMM0 blocks (every 8th
//     block is GEMM0) so convert BW overlaps GEMM0 instead of queueing
//     behind it (was serial 87us).
//   Roles steady: [0,64) lstm | [64,576) gemm.  Prologue grid 4632:
//     idx<4096: (idx&7)==0 -> gemm idx>>3, else convert; 4096..4632 convert.

#define TC       64
#define NCHUNK   8
#define BATCH    256
#define TSEQ     512
#define ISZ      256
#define HSZ      128
#define RB       4
#define NBLK     (BATCH / RB)     // 64 lstm blocks
#define NGB      (2 * TC * 4)     // 512 gemm blocks
#define HROW     144              // shorts; 72 dwords = 8 mod 32 -> 2-way only
#define GX_PER_T 131072           // gx elements per timestep (all 4 planes)
#define GXCH     ((size_t)TC * GX_PER_T)   // shorts per gx buffer
#define STRT     32768            // per-plane step stride in shorts (64*512)

#define XN       (BATCH * TSEQ * ISZ)   // 33554432 x elems
#define WIHN     (4 * HSZ * ISZ)        // 131072
#define WHHN     (4 * HSZ * HSZ)        // 65536
#define NCB      ((XN + WIHN + WHHN) / 8192)   // 4120 convert blocks
#define GRID_PRO 4632                   // 512 gemm + 4120 convert

typedef __attribute__((ext_vector_type(8))) short short8;
typedef __attribute__((ext_vector_type(4))) float f32x4;

__device__ __forceinline__ void barrier_nodrain() {
    // s_barrier WITHOUT the compiler's vmcnt(0) drain: LDS consistency only.
    __asm__ __volatile__("s_waitcnt lgkmcnt(0)\n\ts_barrier" ::: "memory");
}

__device__ __forceinline__ float fast_rcp(float x) {
    return __builtin_amdgcn_rcpf(x);
}
__device__ __forceinline__ float sigmoidf_(float x) {
    return fast_rcp(1.0f + __expf(-x));
}
__device__ __forceinline__ float tanhf_(float x) {
    float e = __expf(2.0f * x);               // inf-safe
    return 1.0f - 2.0f * fast_rcp(e + 1.0f);
}
__device__ __forceinline__ unsigned short f2bf(float x) {  // fp32 -> bf16 RNE
    union { float f; unsigned u; } v; v.f = x;
    unsigned r = v.u + 0x7fffu + ((v.u >> 16) & 1u);
    return (unsigned short)(r >> 16);
}
__device__ __forceinline__ float bfhalf(unsigned wv, int hi) { // bf16 half->f32
    union { unsigned u; float f; } v;
    v.u = hi ? (wv & 0xffff0000u) : (wv << 16);
    return v.f;
}
__device__ __forceinline__ unsigned packbf(float lo, float hi) {  // packed HW cvt
    __hip_bfloat162 h2 = __float22bfloat162_rn(make_float2(lo, hi));
    union { __hip_bfloat162 h; unsigned u; } v; v.h = h2;
    return v.u;
}
__device__ __forceinline__ float sel4(f32x4 v, int r) {   // v[r], 3 cndmask
    float s01 = (r & 1) ? v[1] : v[0];
    float s23 = (r & 1) ? v[3] : v[2];
    return (r & 2) ? s23 : s01;
}

// ---------------------------------------------------------------------------
__global__ __launch_bounds__(512, 4) void fused_kernel(
    const float* __restrict__ x, const float* __restrict__ Wih,
    const float* __restrict__ bih, const float* __restrict__ bhh,
    const float* __restrict__ Whh,
    const unsigned short* __restrict__ gxl, unsigned short* __restrict__ gxg,
    float* __restrict__ hc,
    unsigned short* __restrict__ xb, unsigned short* __restrict__ wihb,
    unsigned short* __restrict__ whhb,
    int t0, int first, int run_lstm, int run_gemm, int use_xbf, int prologue)
{
    __shared__ __align__(16) char smem[32768];
    const int tid  = threadIdx.x;
    const int w    = tid >> 6;
    const int lane = tid & 63;
    const int n    = lane & 15;
    const int quad = lane >> 4;

    int gemm_gb = -1, conv_cb = -1, lstm_blk = -1;
    {
        const int idx = (int)blockIdx.x;
        if (prologue) {
            if (idx < 4096) {
                if ((idx & 7) == 0) gemm_gb = idx >> 3;
                else                conv_cb = idx - (idx >> 3) - 1;
            } else if (idx < GRID_PRO) {
                conv_cb = 3584 + (idx - 4096);
            } else return;
        } else {
            if (idx < NBLK) lstm_blk = idx;
            else            gemm_gb  = idx - NBLK;
        }
    }

    if (conv_cb >= 0) {
        // ===================== CONVERT role (prologue only) =================
        const size_t e0 = ((size_t)conv_cb * 512 + tid) * 16;
        const float* s; unsigned short* d;
        if (e0 < (size_t)XN)              { s = x + e0;                 d = xb + e0; }
        else if (e0 < (size_t)(XN + WIHN)){ s = Wih + (e0 - XN);        d = wihb + (e0 - XN); }
        else                              { s = Whh + (e0 - XN - WIHN); d = whhb + (e0 - XN - WIHN); }
        float4 f0 = *(const float4*)(s);
        float4 f1 = *(const float4*)(s + 4);
        float4 f2 = *(const float4*)(s + 8);
        float4 f3 = *(const float4*)(s + 12);
        *(uint4*)(d)     = (uint4){packbf(f0.x, f0.y), packbf(f0.z, f0.w),
                                   packbf(f1.x, f1.y), packbf(f1.z, f1.w)};
        *(uint4*)(d + 8) = (uint4){packbf(f2.x, f2.y), packbf(f2.z, f2.w),
                                   packbf(f3.x, f3.y), packbf(f3.z, f3.w)};
        return;
    }

    if (gemm_gb >= 0) {
        // ===================== GEMM role (gx for chunk at t0) ===============
        if (!run_gemm) return;
        short* As = (short*)smem;            // [2][128*32] bf16, 16 KB
        short* Bs = (short*)(smem + 16384);  // [2][128*32] bf16, 16 KB

        const int gb = gemm_gb;
        const int nt = gb & 3;               // gate plane
        const int mt = gb >> 2;
        const int tl = mt >> 1;              // timestep within chunk
        const int b0 = (mt & 1) * 128;       // batch half
        const int n0 = nt * 128;

        const int mq = w & 1;                // wave grid 2(m) x 4(n)
        const int nq = w >> 1;

        const int srow = tid >> 2;           // 0..127 staging row
        const int skh  = (tid & 3) * 8;      // elem offset within 32-k slice

        f32x4 acc[4][2];
#pragma unroll
        for (int mi = 0; mi < 4; ++mi)
#pragma unroll
            for (int ni = 0; ni < 2; ++ni)
                acc[mi][ni] = (f32x4){0.f, 0.f, 0.f, 0.f};

        if (use_xbf) {
            // -------- bf16 staging: pure vector load -> LDS store ----------
            const unsigned short* xr = xb + ((size_t)(b0 + srow) * TSEQ + (size_t)(t0 + tl)) * ISZ + skh;
            const unsigned short* wr = wihb + (size_t)(n0 + srow) * ISZ + skh;
            *(short8*)(&As[srow * 32 + skh]) = *(const short8*)(xr);
            *(short8*)(&Bs[srow * 32 + skh]) = *(const short8*)(wr);
            barrier_nodrain();
            for (int ks = 0; ks < 8; ++ks) {
                const int cur = (ks & 1) * 4096;
                const int nxt = 4096 - cur;
                short8 va, vb;
                if (ks < 7) {
                    va = *(const short8*)(xr + (ks + 1) * 32);
                    vb = *(const short8*)(wr + (ks + 1) * 32);
                }
                short8 af[4], bfr[2];
#pragma unroll
                for (int mi = 0; mi < 4; ++mi)
                    af[mi] = *(const short8*)(&As[cur + (mq * 64 + mi * 16 + n) * 32 + quad * 8]);
#pragma unroll
                for (int ni = 0; ni < 2; ++ni)
                    bfr[ni] = *(const short8*)(&Bs[cur + (nq * 32 + ni * 16 + n) * 32 + quad * 8]);
#pragma unroll
                for (int mi = 0; mi < 4; ++mi)
#pragma unroll
                    for (int ni = 0; ni < 2; ++ni)
                        acc[mi][ni] = __builtin_amdgcn_mfma_f32_16x16x32_bf16(
                            af[mi], bfr[ni], acc[mi][ni], 0, 0, 0);
                if (ks < 7) {
                    *(short8*)(&As[nxt + srow * 32 + skh]) = va;
                    *(short8*)(&Bs[nxt + srow * 32 + skh]) = vb;
                }
                barrier_nodrain();
            }
        } else {
            // -------- fp32 staging (prologue chunk 0 only) -----------------
            const float* xrow = x + ((size_t)(b0 + srow) * TSEQ + (size_t)(t0 + tl)) * ISZ + skh;
            const float* wrow = Wih + (size_t)(n0 + srow) * ISZ + skh;
            {
                float4 pa0 = *(const float4*)(xrow);
                float4 pa1 = *(const float4*)(xrow + 4);
                float4 pb0 = *(const float4*)(wrow);
                float4 pb1 = *(const float4*)(wrow + 4);
                *(uint4*)(&As[srow * 32 + skh]) =
                    (uint4){packbf(pa0.x, pa0.y), packbf(pa0.z, pa0.w),
                            packbf(pa1.x, pa1.y), packbf(pa1.z, pa1.w)};
                *(uint4*)(&Bs[srow * 32 + skh]) =
                    (uint4){packbf(pb0.x, pb0.y), packbf(pb0.z, pb0.w),
                            packbf(pb1.x, pb1.y), packbf(pb1.z, pb1.w)};
            }
            barrier_nodrain();
            for (int ks = 0; ks < 8; ++ks) {
                const int cur = (ks & 1) * 4096;
                const int nxt = 4096 - cur;
                float4 pa0, pa1, pb0, pb1;
                if (ks < 7) {
                    pa0 = *(const float4*)(xrow + (ks + 1) * 32);
                    pa1 = *(const float4*)(xrow + (ks + 1) * 32 + 4);
                    pb0 = *(const float4*)(wrow + (ks + 1) * 32);
                    pb1 = *(const float4*)(wrow + (ks + 1) * 32 + 4);
                }
                short8 af[4], bfr[2];
#pragma unroll
                for (int mi = 0; mi < 4; ++mi)
                    af[mi] = *(const short8*)(&As[cur + (mq * 64 + mi * 16 + n) * 32 + quad * 8]);
#pragma unroll
                for (int ni = 0; ni < 2; ++ni)
                    bfr[ni] = *(const short8*)(&Bs[cur + (nq * 32 + ni * 16 + n) * 32 + quad * 8]);
#pragma unroll
                for (int mi = 0; mi < 4; ++mi)
#pragma unroll
                    for (int ni = 0; ni < 2; ++ni)
                        acc[mi][ni] = __builtin_amdgcn_mfma_f32_16x16x32_bf16(
                            af[mi], bfr[ni], acc[mi][ni], 0, 0, 0);
                if (ks < 7) {
                    *(uint4*)(&As[nxt + srow * 32 + skh]) =
                        (uint4){packbf(pa0.x, pa0.y), packbf(pa0.z, pa0.w),
                                packbf(pa1.x, pa1.y), packbf(pa1.z, pa1.w)};
                    *(uint4*)(&Bs[nxt + srow * 32 + skh]) =
                        (uint4){packbf(pb0.x, pb0.y), packbf(pb0.z, pb0.w),
                                packbf(pb1.x, pb1.y), packbf(pb1.z, pb1.w)};
                }
                barrier_nodrain();
            }
        }

        // epilogue: bias + bf16, gate-plane layout, 8-B contiguous stores.
#pragma unroll
        for (int ni = 0; ni < 2; ++ni) {
            const int j    = nq * 32 + ni * 16 + n;
            const int gate = n0 + j;
            const float bias = bih[gate] + bhh[gate];
            const int wj = nq * 2 + ni;                       // j >> 4
#pragma unroll
            for (int mi = 0; mi < 4; ++mi) {
                const int bb   = b0 + mq * 64 + mi * 16 + quad * 4;
                const int blk2 = bb >> 2;
                const size_t idx = ((((size_t)nt * TC + tl) * 64 + blk2) * 512) +
                                   (size_t)wj * 64 + (size_t)n * 4;
                const unsigned lo = packbf(acc[mi][ni][0] + bias, acc[mi][ni][1] + bias);
                const unsigned hi = packbf(acc[mi][ni][2] + bias, acc[mi][ni][3] + bias);
                *(uint2*)(&gxg[idx]) = (uint2){lo, hi};
            }
        }
        return;
    }

    // ======================= LSTM role (2-group pipeline) ===================
    if (!run_lstm) return;
    __builtin_amdgcn_s_setprio(1);   // latency-critical chain wins issue arb
    short* h_lds = (short*)smem;     // rows b=0..3, HROW shorts each (1152 B)

    const int blk   = lstm_blk;
    const int b0    = blk * RB;
    const int jl    = lane >> 2;         // unit j-local 0..15
    const int j     = 16 * w + jl;       // unit hidden index
    const int rsel  = jl & 3;            // D-reg holding this unit's gate
    const int bsel  = lane & 1;          // batch-within-group
    const bool wlane = (lane & 2) == 0;  // dedup writer lanes

    // static A-frags straight from pre-converted bf16 Whh
    short8 Af[4][4];
#pragma unroll
    for (int g = 0; g < 4; ++g) {
        const unsigned short* rowb = whhb + (size_t)(128 * g + 16 * w + n) * HSZ + 8 * quad;
#pragma unroll
        for (int ks = 0; ks < 4; ++ks)
            Af[g][ks] = *(const short8*)(rowb + 32 * ks);
    }

    // unit state: lane owns (j, b=bsel) in group0 and (j, b=2+bsel) in group1
    float cst[2], hl[2];
#pragma unroll
    for (int g = 0; g < 2; ++g) {
        const int b = 2 * g + bsel;
        float cv = 0.f; unsigned short h0 = 0;
        if (!first) {
            cv = hc[(size_t)BATCH * HSZ + (size_t)(b0 + b) * HSZ + j];
            h0 = f2bf(hc[(size_t)(b0 + b) * HSZ + j]);
        }
        cst[g] = cv; hl[g] = 0.f;
        if (wlane) *(unsigned short*)&h_lds[b * HROW + j] = h0;
    }

    // gx: one dwordx2 per plane per step covers all 4 batches of unit jl.
    const unsigned short* gbase = gxl + (size_t)blk * 512 + w * 64 + 4 * jl;
    uint2 gq[2][4];                      // [slot t&1][plane]
#pragma unroll
    for (int s = 0; s < 2; ++s)
#pragma unroll
        for (int p = 0; p < 4; ++p)
            gq[s][p] = *(const uint2*)(gbase + ((size_t)p * TC + s) * STRT);

    barrier_nodrain();

    f32x4 aP0[4], aP1[4];

#define MF_PHASE(grp, A)                                                      \
    do {                                                                      \
        const short* hb_ = h_lds + (2 * (grp) + bsel) * HROW;                 \
        _Pragma("unroll")                                                     \
        for (int ks_ = 0; ks_ < 4; ++ks_) {                                   \
            short8 Bf_ = *(const short8*)(hb_ + 32 * ks_ + 8 * quad);         \
            if (ks_ == 0) {                                                   \
                _Pragma("unroll")                                             \
                for (int g_ = 0; g_ < 4; ++g_)                                \
                    A[g_] = __builtin_amdgcn_mfma_f32_16x16x32_bf16(          \
                        Af[g_][0], Bf_, (f32x4){0.f, 0.f, 0.f, 0.f}, 0, 0, 0);\
            } else {                                                          \
                _Pragma("unroll")                                             \
                for (int g_ = 0; g_ < 4; ++g_)                                \
                    A[g_] = __builtin_amdgcn_mfma_f32_16x16x32_bf16(          \
                        Af[g_][ks_], Bf_, A[g_], 0, 0, 0);                    \
            }                                                                 \
        }                                                                     \
    } while (0)

#define GATES_PHASE(grp, A, S)                                                \
    do {                                                                      \
        const float s0_ = sel4(A[0], rsel) + bfhalf((grp) ? (S)[0].y : (S)[0].x, bsel); \
        const float s1_ = sel4(A[1], rsel) + bfhalf((grp) ? (S)[1].y : (S)[1].x, bsel); \
        const float s2_ = sel4(A[2], rsel) + bfhalf((grp) ? (S)[2].y : (S)[2].x, bsel); \
        const float s3_ = sel4(A[3], rsel) + bfhalf((grp) ? (S)[3].y : (S)[3].x, bsel); \
        const float ig_ = sigmoidf_(s0_);                                     \
        const float fg_ = sigmoidf_(s1_);                                     \
        const float gg_ = tanhf_(s2_);                                        \
        const float og_ = sigmoidf_(s3_);                                     \
        cst[grp] = fg_ * cst[grp] + ig_ * gg_;                                \
        hl[grp]  = og_ * tanhf_(cst[grp]);                                    \
        if (wlane)                                                            \
            *(unsigned short*)&h_lds[(2 * (grp) + bsel) * HROW + j] = f2bf(hl[grp]); \
    } while (0)

#define RELOAD_SLOT(S, tf_)                                                   \
    do {                                                                      \
        const int tc_ = ((tf_) < TC) ? (tf_) : (TC - 1);                      \
        _Pragma("unroll")                                                     \
        for (int p_ = 0; p_ < 4; ++p_)                                        \
            gq[S][p_] = *(const uint2*)(gbase + ((size_t)p_ * TC + tc_) * STRT); \
    } while (0)

    // pipeline prologue: MFMA group0 step 0
    MF_PHASE(0, aP0);
    barrier_nodrain();

    for (int t = 0; t < TC; t += 2) {
        // phase: MFMA g1 (step t)   | gates g0 step t (slot 0)
        MF_PHASE(1, aP1);
        GATES_PHASE(0, aP0, gq[0]);
        barrier_nodrain();

        // phase: MFMA g0 (step t+1) | gates g1 step t; reload slot0 -> t+2
        MF_PHASE(0, aP0);
        GATES_PHASE(1, aP1, gq[0]);
        RELOAD_SLOT(0, t + 2);
        barrier_nodrain();

        // phase: MFMA g1 (step t+1) | gates g0 step t+1 (slot 1)
        MF_PHASE(1, aP1);
        GATES_PHASE(0, aP0, gq[1]);
        barrier_nodrain();

        // phase: MFMA g0 (step t+2; wasted at t=62) | gates g1 step t+1
        MF_PHASE(0, aP0);
        GATES_PHASE(1, aP1, gq[1]);
        RELOAD_SLOT(1, t + 3);
        barrier_nodrain();
    }

#pragma unroll
    for (int g = 0; g < 2; ++g) {
        const int b = 2 * g + bsel;
        if (wlane) {
            hc[(size_t)(b0 + b) * HSZ + j] = hl[g];
            hc[(size_t)BATCH * HSZ + (size_t)(b0 + b) * HSZ + j] = cst[g];
        }
    }
#undef MF_PHASE
#undef GATES_PHASE
#undef RELOAD_SLOT
}

// ---------------------------------------------------------------------------
// MLP head: one block (64 threads) per batch row.
__global__ __launch_bounds__(64) void head_kernel(
    const float* __restrict__ hc,
    const float* __restrict__ W1, const float* __restrict__ b1,
    const float* __restrict__ W2, const float* __restrict__ b2,
    const float* __restrict__ W3, const float* __restrict__ b3,
    float* __restrict__ out)
{
    __shared__ float hs[HSZ];
    __shared__ float o1[64];
    __shared__ float o2[32];
    const int bidx = blockIdx.x;
    const int t = threadIdx.x;
    hs[t]      = hc[bidx * HSZ + t];
    hs[t + 64] = hc[bidx * HSZ + t + 64];
    __syncthreads();
    {
        float a = b1[t];
#pragma unroll 8
        for (int k = 0; k < HSZ; ++k) a += W1[t * HSZ + k] * hs[k];
        o1[t] = fmaxf(a, 0.0f);
    }
    __syncthreads();
    if (t < 32) {
        float a = b2[t];
#pragma unroll 8
        for (int k = 0; k < 64; ++k) a += W2[t * 64 + k] * o1[k];
        o2[t] = fmaxf(a, 0.0f);
    }
    __syncthreads();
    if (t < 4) {
        float a = b3[t];
#pragma unroll
        for (int k = 0; k < 32; ++k) a += W3[t * 32 + k] * o2[k];
        out[bidx * 4 + t] = a;
    }
}

// ---------------------------------------------------------------------------
extern "C" void kernel_launch(void* const* d_in, const int* in_sizes, int n_in,
                              void* d_out, int out_size, void* d_ws, size_t ws_size,
                              hipStream_t stream) {
    const float* x   = (const float*)d_in[0];
    const float* Wih = (const float*)d_in[1];
    const float* Whh = (const float*)d_in[2];
    const float* bih = (const float*)d_in[3];
    const float* bhh = (const float*)d_in[4];
    const float* W1  = (const float*)d_in[5];
    const float* b1  = (const float*)d_in[6];
    const float* W2  = (const float*)d_in[7];
    const float* b2  = (const float*)d_in[8];
    const float* W3  = (const float*)d_in[9];
    const float* b3  = (const float*)d_in[10];
    float* out = (float*)d_out;

    const size_t GXB = GXCH * sizeof(unsigned short);          // 16.78 MB
    unsigned short* gx0 = (unsigned short*)d_ws;
    unsigned short* gx1 = (unsigned short*)((char*)d_ws + GXB);
    float* hc = (float*)((char*)d_ws + 2 * GXB);               // 256 KB
    unsigned short* xb   = (unsigned short*)((char*)d_ws + 2 * GXB + 262144);
    unsigned short* wihb = xb + (size_t)XN;
    unsigned short* whhb = wihb + WIHN;

    // prologue: convert x/Wih/Whh -> bf16 INTERLEAVED with gemm chunk 0 (fp32)
    fused_kernel<<<dim3(GRID_PRO), 512, 0, stream>>>(
        x, Wih, bih, bhh, Whh, gx0, gx0, hc, xb, wihb, whhb,
        0, 1, 0, 1, 0, 1);

    for (int c = 0; c < NCHUNK; ++c) {
        unsigned short* gl = (c & 1) ? gx1 : gx0;   // lstm reads chunk c
        unsigned short* gg = (c & 1) ? gx0 : gx1;   // gemm writes chunk c+1
        fused_kernel<<<dim3(NBLK + NGB), 512, 0, stream>>>(
            x, Wih, bih, bhh, Whh, gl, gg, hc, xb, wihb, whhb,
            (c + 1) * TC, c == 0 ? 1 : 0, 1, (c + 1) < NCHUNK ? 1 : 0, 1, 0);
    }

    head_kernel<<<dim3(BATCH), 64, 0, stream>>>(hc, W1, b1, W2, b2, W3, b3, out);
}

// Round 4
// 571.534 us; speedup vs baseline: 2.1252x; 2.1252x over previous
//
#include <hip/hip_runtime.h>
#include <hip/hip_bf16.h>

// LSTM: B=256, T=512, I=256, H=128 (4H=512 gates), then MLP 128->64->32->4.
// ROUND 12: revert LSTM role to round-2 structure (1 unit/lane, 1 barrier/
//   step — round-3's 2-group pipeline doubled per-wave issue work, 2.2x
//   regression). New schedule, every dispatch single-purpose or known-good:
//     L0 : conv_kernel  (x,Wih,Whh -> bf16; pure BW, ~32us)
//     L1 : fused k=0    (GEMM chunk 0 only, bf16 path)     <- clean-GEMM meas
//     L2..L8 : fused k  (GEMM chunk k + LSTM chunk k-1)
//     L9 : fused k=8    (LSTM chunk 7 only)                <- clean-LSTM meas
//     L10: head
//   LSTM micro-opt: 4-deep MFMA chain split into 2x2 chains + f32x4 add
//   (shaves ~2 MFMA latencies off the step critical path, work-neutral).
//
//   gx gate-plane layout (unchanged):
//     idx(g,t,blk2,wj,L) = (((g*TC+t)*64 + blk2)*512) + wj*64 + L
//     blk2=batch>>2, j=gate&127, wj=j>>4, L=(j&15)*4+(batch&3).

#define TC       64
#define NCHUNK   8
#define BATCH    256
#define TSEQ     512
#define ISZ      256
#define HSZ      128
#define RB       4
#define NBLK     (BATCH / RB)     // 64 lstm blocks
#define NGB      (2 * TC * 4)     // 512 gemm blocks
#define HROW     144              // shorts; 72 dwords = 8 mod 32 -> 2-way only
#define GX_PER_T 131072           // gx elements per timestep (all 4 planes)
#define GXCH     ((size_t)TC * GX_PER_T)   // shorts per gx buffer
#define STRT     32768            // per-plane step stride in shorts (64*512)
#define PF       4                // gx prefetch depth in steps

#define XN       (BATCH * TSEQ * ISZ)   // 33554432 x elems
#define WIHN     (4 * HSZ * ISZ)        // 131072
#define WHHN     (4 * HSZ * HSZ)        // 65536
#define CVT_UNITS ((XN + WIHN + WHHN) / 8)   // 8-elem convert units

typedef __attribute__((ext_vector_type(8))) short short8;
typedef __attribute__((ext_vector_type(4))) float f32x4;

__device__ __forceinline__ void barrier_nodrain() {
    // s_barrier WITHOUT the compiler's vmcnt(0) drain: LDS consistency only.
    __asm__ __volatile__("s_waitcnt lgkmcnt(0)\n\ts_barrier" ::: "memory");
}

__device__ __forceinline__ float fast_rcp(float x) {
    return __builtin_amdgcn_rcpf(x);
}
__device__ __forceinline__ float sigmoidf_(float x) {
    return fast_rcp(1.0f + __expf(-x));
}
__device__ __forceinline__ float tanhf_(float x) {
    float e = __expf(2.0f * x);               // inf-safe
    return 1.0f - 2.0f * fast_rcp(e + 1.0f);
}
__device__ __forceinline__ unsigned short f2bf(float x) {  // fp32 -> bf16 RNE
    union { float f; unsigned u; } v; v.f = x;
    unsigned r = v.u + 0x7fffu + ((v.u >> 16) & 1u);
    return (unsigned short)(r >> 16);
}
__device__ __forceinline__ float bf2f(unsigned short b) {
    union { unsigned u; float f; } v;
    v.u = ((unsigned)b) << 16;
    return v.f;
}
__device__ __forceinline__ unsigned packbf(float lo, float hi) {  // packed HW cvt
    __hip_bfloat162 h2 = __float22bfloat162_rn(make_float2(lo, hi));
    union { __hip_bfloat162 h; unsigned u; } v; v.h = h2;
    return v.u;
}
__device__ __forceinline__ float sel4(f32x4 v, int r) {   // v[r], 3 cndmask
    float s01 = (r & 1) ? v[1] : v[0];
    float s23 = (r & 1) ? v[3] : v[2];
    return (r & 2) ? s23 : s01;
}

// ---------------------------------------------------------------------------
// Convert x / Wih / Whh to bf16 workspace copies. Pure BW (~201 MB).
__global__ __launch_bounds__(256) void conv_kernel(
    const float* __restrict__ x, const float* __restrict__ Wih,
    const float* __restrict__ Whh,
    unsigned short* __restrict__ xb, unsigned short* __restrict__ wihb,
    unsigned short* __restrict__ whhb)
{
    const size_t stride = (size_t)gridDim.x * 256;
    for (size_t u = (size_t)blockIdx.x * 256 + threadIdx.x; u < (size_t)CVT_UNITS;
         u += stride) {
        const size_t e0 = u * 8;
        const float* s; unsigned short* d;
        if (e0 < (size_t)XN)               { s = x + e0;                 d = xb + e0; }
        else if (e0 < (size_t)(XN + WIHN)) { s = Wih + (e0 - XN);        d = wihb + (e0 - XN); }
        else                               { s = Whh + (e0 - XN - WIHN); d = whhb + (e0 - XN - WIHN); }
        float4 f0 = *(const float4*)(s);
        float4 f1 = *(const float4*)(s + 4);
        *(uint4*)(d) = (uint4){packbf(f0.x, f0.y), packbf(f0.z, f0.w),
                               packbf(f1.x, f1.y), packbf(f1.z, f1.w)};
    }
}

// ---------------------------------------------------------------------------
// Fused kernel: blocks [0,NBLK) lstm (chunk reading gxl), [NBLK,..) gemm
// (writing gxg for timestep base t0). Either role can be disabled.
__global__ __launch_bounds__(512, 2) void fused_kernel(
    const unsigned short* __restrict__ xb, const unsigned short* __restrict__ wihb,
    const unsigned short* __restrict__ whhb,
    const float* __restrict__ bih, const float* __restrict__ bhh,
    const unsigned short* __restrict__ gxl, unsigned short* __restrict__ gxg,
    float* __restrict__ hc, int t0, int first, int run_lstm, int run_gemm)
{
    __shared__ __align__(16) char smem[32768];
    const int tid  = threadIdx.x;
    const int w    = tid >> 6;
    const int lane = tid & 63;
    const int n    = lane & 15;
    const int quad = lane >> 4;

    if (blockIdx.x >= NBLK) {
        // ===================== GEMM role (gx for chunk at t0) ===============
        if (!run_gemm) return;
        short* As = (short*)smem;            // [2][128*32] bf16, 16 KB
        short* Bs = (short*)(smem + 16384);  // [2][128*32] bf16, 16 KB

        const int gb = (int)blockIdx.x - NBLK;
        const int nt = gb & 3;               // gate plane
        const int mt = gb >> 2;
        const int tl = mt >> 1;              // timestep within chunk
        const int b0 = (mt & 1) * 128;       // batch half
        const int n0 = nt * 128;

        const int mq = w & 1;                // wave grid 2(m) x 4(n)
        const int nq = w >> 1;

        const int srow = tid >> 2;           // 0..127 staging row
        const int skh  = (tid & 3) * 8;      // elem offset within 32-k slice

        const unsigned short* xr = xb + ((size_t)(b0 + srow) * TSEQ + (size_t)(t0 + tl)) * ISZ + skh;
        const unsigned short* wr = wihb + (size_t)(n0 + srow) * ISZ + skh;

        f32x4 acc[4][2];
#pragma unroll
        for (int mi = 0; mi < 4; ++mi)
#pragma unroll
            for (int ni = 0; ni < 2; ++ni)
                acc[mi][ni] = (f32x4){0.f, 0.f, 0.f, 0.f};

        *(short8*)(&As[srow * 32 + skh]) = *(const short8*)(xr);
        *(short8*)(&Bs[srow * 32 + skh]) = *(const short8*)(wr);
        barrier_nodrain();

        for (int ks = 0; ks < 8; ++ks) {
            const int cur = (ks & 1) * 4096;
            const int nxt = 4096 - cur;
            short8 va, vb;
            if (ks < 7) {
                va = *(const short8*)(xr + (ks + 1) * 32);
                vb = *(const short8*)(wr + (ks + 1) * 32);
            }
            short8 af[4], bfr[2];
#pragma unroll
            for (int mi = 0; mi < 4; ++mi)
                af[mi] = *(const short8*)(&As[cur + (mq * 64 + mi * 16 + n) * 32 + quad * 8]);
#pragma unroll
            for (int ni = 0; ni < 2; ++ni)
                bfr[ni] = *(const short8*)(&Bs[cur + (nq * 32 + ni * 16 + n) * 32 + quad * 8]);
#pragma unroll
            for (int mi = 0; mi < 4; ++mi)
#pragma unroll
                for (int ni = 0; ni < 2; ++ni)
                    acc[mi][ni] = __builtin_amdgcn_mfma_f32_16x16x32_bf16(
                        af[mi], bfr[ni], acc[mi][ni], 0, 0, 0);
            if (ks < 7) {
                *(short8*)(&As[nxt + srow * 32 + skh]) = va;
                *(short8*)(&Bs[nxt + srow * 32 + skh]) = vb;
            }
            barrier_nodrain();
        }

        // epilogue: bias + bf16, gate-plane layout, 8-B contiguous stores.
#pragma unroll
        for (int ni = 0; ni < 2; ++ni) {
            const int j    = nq * 32 + ni * 16 + n;
            const int gate = n0 + j;
            const float bias = bih[gate] + bhh[gate];
            const int wj = nq * 2 + ni;                       // j >> 4
#pragma unroll
            for (int mi = 0; mi < 4; ++mi) {
                const int bb   = b0 + mq * 64 + mi * 16 + quad * 4;
                const int blk2 = bb >> 2;
                const size_t idx = ((((size_t)nt * TC + tl) * 64 + blk2) * 512) +
                                   (size_t)wj * 64 + (size_t)n * 4;
                const unsigned lo = packbf(acc[mi][ni][0] + bias, acc[mi][ni][1] + bias);
                const unsigned hi = packbf(acc[mi][ni][2] + bias, acc[mi][ni][3] + bias);
                *(uint2*)(&gxg[idx]) = (uint2){lo, hi};
            }
        }
        return;
    }

    // ======================= LSTM role (round-2 structure) ==================
    if (!run_lstm) return;
    __builtin_amdgcn_s_setprio(1);   // latency-critical chain wins issue arb
    short* h_lds = (short*)smem;     // [2*RB*HROW] bf16 double-buffered h

    const int blk  = (int)blockIdx.x;
    const int b0   = blk * RB;
    const int nb   = lane & 3;           // unit batch
    const int jl   = lane >> 2;          // unit j-local 0..15
    const int j    = 16 * w + jl;        // unit hidden index
    const int rsel = jl & 3;             // D-reg holding this unit's gate

    // static A-frags straight from pre-converted bf16 Whh
    short8 Af[4][4];
#pragma unroll
    for (int g = 0; g < 4; ++g) {
        const unsigned short* rowb = whhb + (size_t)(128 * g + 16 * w + n) * HSZ + 8 * quad;
#pragma unroll
        for (int ks = 0; ks < 4; ++ks)
            Af[g][ks] = *(const short8*)(rowb + 32 * ks);
    }

    // init unit state: every thread owns one (j, b) unit
    float c1 = 0.f, hl1 = 0.f;
    {
        unsigned short h0 = 0;
        if (!first) {
            c1 = hc[(size_t)BATCH * HSZ + (size_t)(b0 + nb) * HSZ + j];
            h0 = f2bf(hc[(size_t)(b0 + nb) * HSZ + j]);
        }
        *(unsigned short*)&h_lds[nb * HROW + j] = h0;   // buffer 0
    }

    // gx: 4 coalesced ushort loads per lane per step (one per gate plane)
    const unsigned short* gp[4];
#pragma unroll
    for (int g = 0; g < 4; ++g)
        gp[g] = gxl + (((size_t)g * TC) * 64 + blk) * 512 + (size_t)w * 64 + lane;

    unsigned short gq[PF][4];
#pragma unroll
    for (int d = 0; d < PF; ++d)
#pragma unroll
        for (int g = 0; g < 4; ++g)
            gq[d][g] = gp[g][(size_t)d * STRT];

    barrier_nodrain();

    for (int t = 0; t < TC; t += PF) {
#pragma unroll
        for (int u = 0; u < PF; ++u) {
            const int tt = t + u;
            const short* hb_r = h_lds + (u & 1) * (RB * HROW);
            short*       hb_w = h_lds + ((u & 1) ^ 1) * (RB * HROW);

            short8 Bf[4];
#pragma unroll
            for (int ks = 0; ks < 4; ++ks)
                Bf[ks] = *(const short8*)(&hb_r[nb * HROW + 32 * ks + 8 * quad]);

            // MFMAs: two independent 2-deep chains per gate, then one add.
            f32x4 acc[4], acc2[4];
#pragma unroll
            for (int g = 0; g < 4; ++g)
                acc[g] = __builtin_amdgcn_mfma_f32_16x16x32_bf16(
                    Af[g][0], Bf[0], (f32x4){0.f, 0.f, 0.f, 0.f}, 0, 0, 0);
#pragma unroll
            for (int g = 0; g < 4; ++g)
                acc2[g] = __builtin_amdgcn_mfma_f32_16x16x32_bf16(
                    Af[g][1], Bf[1], (f32x4){0.f, 0.f, 0.f, 0.f}, 0, 0, 0);
#pragma unroll
            for (int g = 0; g < 4; ++g)
                acc[g] = __builtin_amdgcn_mfma_f32_16x16x32_bf16(
                    Af[g][2], Bf[2], acc[g], 0, 0, 0);
#pragma unroll
            for (int g = 0; g < 4; ++g)
                acc2[g] = __builtin_amdgcn_mfma_f32_16x16x32_bf16(
                    Af[g][3], Bf[3], acc2[g], 0, 0, 0);
#pragma unroll
            for (int g = 0; g < 4; ++g)
                acc[g] = acc[g] + acc2[g];

            // in-lane gate extract: unit (jl,nb)'s value is THIS lane's
            // acc[g][rsel] (D row = 4*quad+reg = jl, D col batch = nb).
            const float s0 = sel4(acc[0], rsel) + bf2f(gq[u][0]);
            const float s1 = sel4(acc[1], rsel) + bf2f(gq[u][1]);
            const float s2 = sel4(acc[2], rsel) + bf2f(gq[u][2]);
            const float s3 = sel4(acc[3], rsel) + bf2f(gq[u][3]);

            // reload ring slot u (just consumed) for step tt+PF; vmcnt wait
            // for these loads lands PF steps from now.
            const int tf = (tt + PF < TC) ? (tt + PF) : (TC - 1);
#pragma unroll
            for (int g = 0; g < 4; ++g)
                gq[u][g] = gp[g][(size_t)tf * STRT];

            const float ig = sigmoidf_(s0);
            const float fg = sigmoidf_(s1);
            const float gg = tanhf_(s2);
            const float og = sigmoidf_(s3);
            c1  = fg * c1 + ig * gg;
            hl1 = og * tanhf_(c1);

            *(unsigned short*)&hb_w[nb * HROW + j] = f2bf(hl1);
            barrier_nodrain();
        }
    }

    hc[(size_t)(b0 + nb) * HSZ + j] = hl1;
    hc[(size_t)BATCH * HSZ + (size_t)(b0 + nb) * HSZ + j] = c1;
}

// ---------------------------------------------------------------------------
// MLP head: one block (64 threads) per batch row.
__global__ __launch_bounds__(64) void head_kernel(
    const float* __restrict__ hc,
    const float* __restrict__ W1, const float* __restrict__ b1,
    const float* __restrict__ W2, const float* __restrict__ b2,
    const float* __restrict__ W3, const float* __restrict__ b3,
    float* __restrict__ out)
{
    __shared__ float hs[HSZ];
    __shared__ float o1[64];
    __shared__ float o2[32];
    const int bidx = blockIdx.x;
    const int t = threadIdx.x;
    hs[t]      = hc[bidx * HSZ + t];
    hs[t + 64] = hc[bidx * HSZ + t + 64];
    __syncthreads();
    {
        float a = b1[t];
#pragma unroll 8
        for (int k = 0; k < HSZ; ++k) a += W1[t * HSZ + k] * hs[k];
        o1[t] = fmaxf(a, 0.0f);
    }
    __syncthreads();
    if (t < 32) {
        float a = b2[t];
#pragma unroll 8
        for (int k = 0; k < 64; ++k) a += W2[t * 64 + k] * o1[k];
        o2[t] = fmaxf(a, 0.0f);
    }
    __syncthreads();
    if (t < 4) {
        float a = b3[t];
#pragma unroll
        for (int k = 0; k < 32; ++k) a += W3[t * 32 + k] * o2[k];
        out[bidx * 4 + t] = a;
    }
}

// ---------------------------------------------------------------------------
extern "C" void kernel_launch(void* const* d_in, const int* in_sizes, int n_in,
                              void* d_out, int out_size, void* d_ws, size_t ws_size,
                              hipStream_t stream) {
    const float* x   = (const float*)d_in[0];
    const float* Wih = (const float*)d_in[1];
    const float* Whh = (const float*)d_in[2];
    const float* bih = (const float*)d_in[3];
    const float* bhh = (const float*)d_in[4];
    const float* W1  = (const float*)d_in[5];
    const float* b1  = (const float*)d_in[6];
    const float* W2  = (const float*)d_in[7];
    const float* b2  = (const float*)d_in[8];
    const float* W3  = (const float*)d_in[9];
    const float* b3  = (const float*)d_in[10];
    float* out = (float*)d_out;

    const size_t GXB = GXCH * sizeof(unsigned short);          // 16.78 MB
    unsigned short* gx0 = (unsigned short*)d_ws;
    unsigned short* gx1 = (unsigned short*)((char*)d_ws + GXB);
    float* hc = (float*)((char*)d_ws + 2 * GXB);               // 256 KB
    unsigned short* xb   = (unsigned short*)((char*)d_ws + 2 * GXB + 262144);
    unsigned short* wihb = xb + (size_t)XN;
    unsigned short* whhb = wihb + WIHN;

    // L0: fp32 -> bf16 conversion (pure BW)
    conv_kernel<<<dim3(2048), 256, 0, stream>>>(x, Wih, Whh, xb, wihb, whhb);

    // L1..L9: skewed pipeline. Launch k: GEMM(chunk k) + LSTM(chunk k-1).
    for (int k = 0; k <= NCHUNK; ++k) {
        const int run_gemm = (k < NCHUNK);
        const int run_lstm = (k > 0);
        unsigned short* gg = (k & 1) ? gx1 : gx0;        // gemm writes chunk k
        const unsigned short* gl = ((k - 1) & 1) ? gx1 : gx0; // lstm reads k-1
        fused_kernel<<<dim3(NBLK + NGB), 512, 0, stream>>>(
            xb, wihb, whhb, bih, bhh, gl, gg, hc,
            k * TC, (k == 1) ? 1 : 0, run_lstm, run_gemm);
    }

    head_kernel<<<dim3(BATCH), 64, 0, stream>>>(hc, W1, b1, W2, b2, W3, b3, out);
}